// Round 20
// baseline (93.900 us; speedup 1.0000x reference)
//
#include <hip/hip_runtime.h>
#include <hip/hip_bf16.h>

// Conv2d 3x3 s1 p1, NCHW/OIHW fp32 -> fp32. bf16 implicit GEMM.
// R19: steps contain ZERO VMEM (pure ds_read+MFMA). All staging (W panel
// 24KB -> LDS ping-pong bank, input rows -> 8-slot ring) issues at phase
// top, W first; vmcnt(0)+barrier per top waits only on >=1-phase-old loads.
// Fixes R11-R16's hidden stall: compiler W-waits were draining input
// stages with sub-phase slack.

#define C_IN   128
#define K_OUT  256
#define HW     56
#define IMG    3136
#define NBATCH 32
#define PW     58
#define IN_WS_USHORT ((size_t)4*NBATCH*PW*256*8)     // [cq][n][py][256ch][8]
#define WT_WS_USHORT ((size_t)12*2*1536*8)           // [p][koh][1536ch][8]

typedef __bf16 bf16x8 __attribute__((ext_vector_type(8)));
typedef float  f32x4  __attribute__((ext_vector_type(4)));
typedef unsigned short ushort8 __attribute__((ext_vector_type(8)));

__device__ inline unsigned short f2bf(float f) {
    unsigned int u = __builtin_bit_cast(unsigned int, f);
    u += ((u >> 16) & 1u) + 0x7FFFu;   // RNE
    return (unsigned short)(u >> 16);
}

__device__ __forceinline__ void gl2lds16(const unsigned short* g, unsigned short* l) {
    __builtin_amdgcn_global_load_lds(
        (const __attribute__((address_space(1))) unsigned int*)g,
        (__attribute__((address_space(3))) unsigned int*)l, 16, 0, 0);
}

// ---- prep A: NCHW fp32 -> [cq][n][py][Xq:4][cc:4][Xr:16][8c] bf16 ----
__global__ void prep_input(const float* __restrict__ inp,
                           unsigned short* __restrict__ dst) {
    __shared__ unsigned short tile[C_IN * 57];   // [c][x], stride 57
    int n = blockIdx.x / PW, py = blockIdx.x % PW;
    ushort8* d8 = (ushort8*)dst;
    const bool border = (py == 0 || py == PW - 1);
    if (!border) {
        const float* src = inp + (size_t)n * C_IN * IMG + (py - 1) * HW;
        for (int i = threadIdx.x; i < C_IN * HW; i += 256) {
            int c = i / HW, x = i - c * HW;      // coalesced read along x
            tile[c * 57 + x] = f2bf(src[c * IMG + x]);
        }
        __syncthreads();
    }
    for (int i = threadIdx.x; i < 1024; i += 256) {     // 4 cq x 256 chunks
        int cq = i >> 8, rem = i & 255;
        int X = ((rem >> 6) & 3) * 16 + (rem & 15);
        int cc = (rem >> 4) & 3;
        ushort8 v = (ushort8)0;
        if (!border && X >= 1 && X <= HW) {
#pragma unroll
            for (int e = 0; e < 8; ++e)
                v[e] = tile[(cq * 32 + cc * 8 + e) * 57 + (X - 1)];
        }
        d8[((size_t)(cq * NBATCH + n) * PW + py) * 256 + rem] = v;
    }
}

// ---- prep B: OIHW fp32 -> [p=cq*3+r][koh:2][s:3][koq:8][cc:4][kor:16][8c] ----
__global__ void prep_weights(const float* __restrict__ w,
                             unsigned short* __restrict__ dst) {
    int chunk = blockIdx.x * 256 + threadIdx.x;  // 36864 chunks
    int p = chunk / 3072, rem = chunk - p * 3072;
    int koh = rem / 1536, rem2 = rem - koh * 1536;
    int s = rem2 / 512, rem3 = rem2 - s * 512;
    int koq = rem3 >> 6, cc = (rem3 >> 4) & 3, kor = rem3 & 15;
    int ko = koh * 128 + koq * 16 + kor;
    int cq = p / 3, r = p - 3 * cq;
    ushort8 v;
#pragma unroll
    for (int e = 0; e < 8; ++e)
        v[e] = f2bf(w[(ko * C_IN + cq * 32 + cc * 8 + e) * 9 + r * 3 + s]);
    ((ushort8*)dst)[chunk] = v;
}

// ---- main conv ----
// Block: 2 waves; wave wv owns ko [wv*64, wv*64+64); 112 px (2 rows).
// LDS (ushort idx): W bank0 [0,12288) bank1 [12288,24576)  (24KB each)
//                   input ring [24576,40960)  8 slots x 2048 ushorts
// W bank layout (16B chunks): [s:3][koq:8][cc:4][kor:16] -> conflict-free.
// Phase P: vmcnt(0); barrier; stage W panel P+1 (12 block-iters); stage
// input rows; 3 steps of {4 A-dsread, 7 B-dsread, 28 MFMA} (no VMEM).
__global__ __launch_bounds__(128, 2) void conv_mfma(
        const unsigned short* __restrict__ In,
        const unsigned short* __restrict__ Wt,
        const float* __restrict__ bias,
        float* __restrict__ out) {
    __shared__ unsigned short smem[40960];       // 80 KB

    const int tid = threadIdx.x;
    const int lane = tid & 63, wv = tid >> 6;    // wv in {0,1}
    const int l15 = lane & 15, lk = lane >> 4;
    const int koh = blockIdx.y;
    const int by = blockIdx.x;                   // 0..895
    const int n = by / 28, rb = (by % 28) * 2;   // 2 image rows per block

    const int abase = wv * 4096 + lk * 256 + l15 * 16;   // A byte off in slice

    int yl[7], xp[3][7];
#pragma unroll
    for (int nf = 0; nf < 7; ++nf) {
        int p = nf * 16 + l15;                   // local pixel 0..111
        yl[nf] = p / 56;
        int x = p - yl[nf] * 56;
#pragma unroll
        for (int s = 0; s < 3; ++s) {
            int X = x + s;
            xp[s][nf] = ((X >> 4) << 10) + lk * 256 + ((X & 15) << 4);
        }
    }

    f32x4 acc[4][7];
#pragma unroll
    for (int m = 0; m < 4; ++m)
#pragma unroll
        for (int nf = 0; nf < 7; ++nf) acc[m][nf] = (f32x4)0.0f;

// stage W panel P_ (p index) into LDS bank P_&1 (24KB, linear copy)
#define STAGE_W(P_) do {                                                    \
    const unsigned short* wg = Wt + ((size_t)((P_) * 2 + koh)) * 12288;     \
    unsigned short* wl = &smem[((P_) & 1) * 12288];                         \
    _Pragma("unroll")                                                       \
    for (int i = 0; i < 12; ++i)                                            \
        gl2lds16(wg + i * 1024 + tid * 8, wl + i * 1024 + tid * 8);         \
} while (0)

// stage padded row rb+T_ of c-quarter C_ into ring slot (4C_+T_)&7
#define STAGE_ROW(C_, T_) do {                                              \
    const unsigned short* gsrc =                                            \
        In + ((size_t)(((C_) * NBATCH + n) * PW + rb + (T_))) * 2048;       \
    unsigned short* ldst = &smem[24576 + ((4 * (C_) + (T_)) & 7) * 2048];   \
    gl2lds16(gsrc + tid * 8, ldst + tid * 8);                               \
    gl2lds16(gsrc + 1024 + tid * 8, ldst + 1024 + tid * 8);                 \
} while (0)

#define STEP(PH, S_) do {                                                   \
    const char* wb = (const char*)smem + ((PH) & 1) * 24576 + (S_) * 8192;  \
    const char* ib = (const char*)smem + 49152;                             \
    bf16x8 a[4], b[7];                                                      \
    _Pragma("unroll")                                                       \
    for (int m = 0; m < 4; ++m)                                             \
        a[m] = *(const bf16x8*)(wb + abase + m * 1024);                     \
    _Pragma("unroll")                                                       \
    for (int nf = 0; nf < 7; ++nf)                                          \
        b[nf] = *(const bf16x8*)(ib + roff[nf] + xp[(S_)][nf]);             \
    __builtin_amdgcn_s_setprio(1);                                          \
    _Pragma("unroll")                                                       \
    for (int m = 0; m < 4; ++m)                                             \
        _Pragma("unroll")                                                   \
        for (int nf = 0; nf < 7; ++nf)                                      \
            acc[m][nf] = __builtin_amdgcn_mfma_f32_16x16x32_bf16(           \
                a[m], b[nf], acc[m][nf], 0, 0, 0);                          \
    __builtin_amdgcn_s_setprio(0);                                          \
} while (0)

    // prologue: W panel 0 -> bank 0, input rows 0..3 of cq 0
    STAGE_W(0);
    STAGE_ROW(0, 0); STAGE_ROW(0, 1); STAGE_ROW(0, 2); STAGE_ROW(0, 3);

#define PHASE(PH) do {                                                      \
    constexpr int cqp_ = (PH) / 3, rp_ = (PH) % 3;                          \
    asm volatile("s_waitcnt vmcnt(0)" ::: "memory");                        \
    asm volatile("s_barrier" ::: "memory");                                 \
    if constexpr ((PH) < 11) STAGE_W((PH) + 1);                             \
    if constexpr (cqp_ < 3) {                                               \
        if constexpr (rp_ == 0) { STAGE_ROW(cqp_ + 1, 0); STAGE_ROW(cqp_ + 1, 1); } \
        if constexpr (rp_ == 1) { STAGE_ROW(cqp_ + 1, 2); STAGE_ROW(cqp_ + 1, 3); } \
    }                                                                       \
    asm volatile("" ::: "memory");                                          \
    { int roff[7];                                                          \
      _Pragma("unroll")                                                     \
      for (int nf = 0; nf < 7; ++nf)                                        \
          roff[nf] = ((4 * cqp_ + rp_ + yl[nf]) & 7) << 12;                 \
      STEP(PH, 0); STEP(PH, 1); STEP(PH, 2);                                \
    }                                                                       \
} while (0)

    PHASE(0);  PHASE(1);  PHASE(2);  PHASE(3);
    PHASE(4);  PHASE(5);  PHASE(6);  PHASE(7);
    PHASE(8);  PHASE(9);  PHASE(10); PHASE(11);

#undef PHASE
#undef STEP
#undef STAGE_ROW
#undef STAGE_W

    // epilogue: D col = l15 (pixel), row = lk*4 + j (ko)
    const int sp0 = rb * 56;                     // block pixel base (2 rows)
#pragma unroll
    for (int m = 0; m < 4; ++m) {
        int kb = koh * 128 + wv * 64 + m * 16 + lk * 4;
        f32x4 bs = *(const f32x4*)(bias + kb);
#pragma unroll
        for (int nf = 0; nf < 7; ++nf) {
            float* ob = out + ((size_t)(n * K_OUT + kb) * IMG) + sp0 + nf * 16 + l15;
#pragma unroll
            for (int j = 0; j < 4; ++j)
                ob[(size_t)j * IMG] = acc[m][nf][j] + bs[j];
        }
    }
}

// ---- fallback (only if ws too small): naive fp32 direct conv ----
__global__ void conv_naive(const float* __restrict__ inp,
                           const float* __restrict__ ker,
                           const float* __restrict__ bias,
                           float* __restrict__ out, int total) {
    int o = blockIdx.x * blockDim.x + threadIdx.x;
    if (o >= total) return;
    int x = o % HW, y = (o / HW) % HW, ko = (o / IMG) % K_OUT, n = o / (IMG * K_OUT);
    float acc = bias[ko];
    for (int c = 0; c < C_IN; ++c)
        for (int r = 0; r < 3; ++r) {
            int iy = y + r - 1; if ((unsigned)iy >= HW) continue;
            for (int s = 0; s < 3; ++s) {
                int ix = x + s - 1; if ((unsigned)ix >= HW) continue;
                acc += inp[((n * C_IN + c) * HW + iy) * HW + ix]
                     * ker[((ko * C_IN + c) * 3 + r) * 3 + s];
            }
        }
    out[o] = acc;
}

extern "C" void kernel_launch(void* const* d_in, const int* in_sizes, int n_in,
                              void* d_out, int out_size, void* d_ws, size_t ws_size,
                              hipStream_t stream) {
    const float* inp  = (const float*)d_in[0];
    const float* ker  = (const float*)d_in[1];
    const float* bias = (const float*)d_in[2];
    float* out = (float*)d_out;

    const size_t need = (IN_WS_USHORT + WT_WS_USHORT) * 2;
    if (ws_size < need) {
        int total = NBATCH * K_OUT * IMG;
        conv_naive<<<(total + 255) / 256, 256, 0, stream>>>(inp, ker, bias, out, total);
        return;
    }

    unsigned short* inb = (unsigned short*)d_ws;
    unsigned short* wtb = inb + IN_WS_USHORT;

    prep_input<<<NBATCH * PW, 256, 0, stream>>>(inp, inb);
    prep_weights<<<144, 256, 0, stream>>>(ker, wtb);

    conv_mfma<<<dim3(896, 2), 128, 0, stream>>>(inb, wtb, bias, out);
}

// Round 21
// 85.482 us; speedup vs baseline: 1.0985x; 1.0985x over previous
//
#include <hip/hip_runtime.h>
#include <hip/hip_bf16.h>

// Conv2d 3x3 s1 p1, NCHW/OIHW fp32 -> fp32. bf16 implicit GEMM.
// R20: m201-style 8-phase template port. 512-thr blocks (8 waves,
// 256ko x 224px), 36 sub-phases (cq,r,s): {11 ds_reads; stage (W slice p+2
// -> 4-slot ring, input rows -> 12-slot ring); counted vmcnt; barrier;
// 28-MFMA cluster (setprio); barrier}. LDS 112KB. Never vmcnt(0) mid-loop.

#define C_IN   128
#define K_OUT  256
#define HW     56
#define IMG    3136
#define NBATCH 32
#define PW     58
#define IN_WS_USHORT ((size_t)4*NBATCH*PW*256*8)     // [cq][n][py][256ch][8]
#define WT_WS_USHORT ((size_t)36*1024*8)             // [p:36][koq][cc][kor][8]

typedef __bf16 bf16x8 __attribute__((ext_vector_type(8)));
typedef float  f32x4  __attribute__((ext_vector_type(4)));
typedef unsigned short ushort8 __attribute__((ext_vector_type(8)));

__device__ inline unsigned short f2bf(float f) {
    unsigned int u = __builtin_bit_cast(unsigned int, f);
    u += ((u >> 16) & 1u) + 0x7FFFu;   // RNE
    return (unsigned short)(u >> 16);
}

__device__ __forceinline__ void gl2lds16(const unsigned short* g, unsigned short* l) {
    __builtin_amdgcn_global_load_lds(
        (const __attribute__((address_space(1))) unsigned int*)g,
        (__attribute__((address_space(3))) unsigned int*)l, 16, 0, 0);
}

// ---- prep A: NCHW fp32 -> [cq][n][py][Xq:4][cc:4][Xr:16][8c] bf16 ----
__global__ void prep_input(const float* __restrict__ inp,
                           unsigned short* __restrict__ dst) {
    __shared__ unsigned short tile[C_IN * 57];   // [c][x], stride 57
    int n = blockIdx.x / PW, py = blockIdx.x % PW;
    ushort8* d8 = (ushort8*)dst;
    const bool border = (py == 0 || py == PW - 1);
    if (!border) {
        const float* src = inp + (size_t)n * C_IN * IMG + (py - 1) * HW;
        for (int i = threadIdx.x; i < C_IN * HW; i += 256) {
            int c = i / HW, x = i - c * HW;      // coalesced read along x
            tile[c * 57 + x] = f2bf(src[c * IMG + x]);
        }
        __syncthreads();
    }
    for (int i = threadIdx.x; i < 1024; i += 256) {     // 4 cq x 256 chunks
        int cq = i >> 8, rem = i & 255;
        int X = ((rem >> 6) & 3) * 16 + (rem & 15);
        int cc = (rem >> 4) & 3;
        ushort8 v = (ushort8)0;
        if (!border && X >= 1 && X <= HW) {
#pragma unroll
            for (int e = 0; e < 8; ++e)
                v[e] = tile[(cq * 32 + cc * 8 + e) * 57 + (X - 1)];
        }
        d8[((size_t)(cq * NBATCH + n) * PW + py) * 256 + rem] = v;
    }
}

// ---- prep B: OIHW fp32 -> [p=(cq*3+r)*3+s][koq:16][cc:4][kor:16][8c] ----
__global__ void prep_weights(const float* __restrict__ w,
                             unsigned short* __restrict__ dst) {
    int chunk = blockIdx.x * 256 + threadIdx.x;  // 36864 chunks
    int p = chunk >> 10, rem = chunk & 1023;
    int koq = rem >> 6, cc = (rem >> 4) & 3, kor = rem & 15;
    int ko = koq * 16 + kor;
    int cq = p / 9, rs = p % 9;                  // rs = r*3+s
    int c0 = cq * 32 + cc * 8;
    ushort8 v;
#pragma unroll
    for (int e = 0; e < 8; ++e)
        v[e] = f2bf(w[(ko * C_IN + c0 + e) * 9 + rs]);
    ((ushort8*)dst)[chunk] = v;
}

// ---- main conv: 8-phase-template structure ----
// Block: 512 thr, 8 waves; wave (wr=wv>>1, wc=wv&1) owns ko [wr*64..+64),
// px [wc*112..+112). Tile 256ko x 224px (4 image rows).
// LDS bytes: W ring 4 x 16KB [0,65536); input ring 12 x 4KB [65536,114688).
// W slice p = (cq*3+r)*3+s, layout [koq:16][cc:4][kor:16] (conflict-free).
// Input slot = (6cq + t) % 12, t = padded row rb+t.
__global__ __launch_bounds__(512, 2) void conv_mfma(
        const unsigned short* __restrict__ In,
        const unsigned short* __restrict__ Wt,
        const float* __restrict__ bias,
        float* __restrict__ out) {
    __shared__ unsigned short smem[57344];       // 112 KB

    const int tid = threadIdx.x;
    const int lane = tid & 63, wv = tid >> 6;
    const int l15 = lane & 15, lk = lane >> 4;
    const int wr = wv >> 1, wc = wv & 1;
    const int by = blockIdx.x;                   // 0..447
    const int n = by / 14, rb = (by % 14) * 4;

    const int albase = wr * 4096 + lk * 256 + l15 * 16;   // + m*1024 + slot

    int yl[7], xp[3][7];
#pragma unroll
    for (int nf = 0; nf < 7; ++nf) {
        int p = wc * 112 + nf * 16 + l15;        // local pixel 0..223
        yl[nf] = p / 56;
        int x = p - yl[nf] * 56;
#pragma unroll
        for (int s = 0; s < 3; ++s) {
            int X = x + s;
            xp[s][nf] = ((X >> 4) << 10) + lk * 256 + ((X & 15) << 4);
        }
    }

    f32x4 acc[4][7];
#pragma unroll
    for (int m = 0; m < 4; ++m)
#pragma unroll
        for (int nf = 0; nf < 7; ++nf) acc[m][nf] = (f32x4)0.0f;

// stage W slice P_ (16KB) into ring slot P_&3: 2 rounds of 512thr x 16B
#define STAGE_W(P_) do {                                                    \
    const unsigned short* wg = Wt + (size_t)(P_) * 8192 + tid * 8;          \
    unsigned short* wl = &smem[((P_) & 3) * 8192 + tid * 8];                \
    gl2lds16(wg, wl);                                                       \
    gl2lds16(wg + 4096, wl + 4096);                                         \
} while (0)

// stage rows T_,T_+1 of c-quarter CQ_: waves 0-3 row T_, waves 4-7 row T_+1
#define STAGE_ROWS2(CQ_, T_) do {                                           \
    int t_ = (T_) + (wv >> 2);                                              \
    int slot_ = (6 * (CQ_) + t_) % 12;                                      \
    const unsigned short* gsrc =                                            \
        In + ((size_t)(((CQ_) * NBATCH + n) * PW + rb + t_)) * 2048         \
           + (wv & 3) * 512 + lane * 8;                                     \
    unsigned short* ldst = &smem[32768 + slot_ * 2048 + (wv & 3) * 512 + lane * 8]; \
    gl2lds16(gsrc, ldst);                                                   \
} while (0)

#define SUBPHASE(P) do {                                                    \
    constexpr int cq_ = (P) / 9, r_ = ((P) % 9) / 3, s_ = (P) % 3;          \
    bf16x8 a[4], b[7];                                                      \
    { const char* wbp = (const char*)smem + ((P) & 3) * 16384;              \
      _Pragma("unroll")                                                     \
      for (int m = 0; m < 4; ++m)                                           \
          a[m] = *(const bf16x8*)(wbp + albase + m * 1024);                 \
      const char* ibp = (const char*)smem + 65536;                          \
      _Pragma("unroll")                                                     \
      for (int nf = 0; nf < 7; ++nf) {                                      \
          int t = 6 * cq_ + r_ + yl[nf]; if (t >= 12) t -= 12;              \
          b[nf] = *(const bf16x8*)(ibp + (t << 12) + xp[s_][nf]);           \
      }                                                                     \
    }                                                                       \
    if constexpr ((P) + 2 <= 35) STAGE_W((P) + 2);                          \
    if constexpr (r_ == 0 && cq_ < 3) STAGE_ROWS2(cq_ + 1, 2 * s_);         \
    { constexpr int cP = (((P) + 2 <= 35) ? 2 : 0)                          \
                       + ((r_ == 0 && cq_ < 3) ? 1 : 0);                    \
      asm volatile("s_waitcnt vmcnt(%0)" :: "i"(cP) : "memory"); }          \
    asm volatile("s_barrier" ::: "memory");                                 \
    __builtin_amdgcn_s_setprio(1);                                          \
    _Pragma("unroll")                                                       \
    for (int m = 0; m < 4; ++m)                                             \
        _Pragma("unroll")                                                   \
        for (int nf = 0; nf < 7; ++nf)                                      \
            acc[m][nf] = __builtin_amdgcn_mfma_f32_16x16x32_bf16(           \
                a[m], b[nf], acc[m][nf], 0, 0, 0);                          \
    __builtin_amdgcn_s_setprio(0);                                          \
    asm volatile("s_barrier" ::: "memory");                                 \
} while (0)

    // prologue: rows t0..5 of cq0, W slices 0,1; drain all but W1
    STAGE_ROWS2(0, 0); STAGE_ROWS2(0, 2); STAGE_ROWS2(0, 4);
    STAGE_W(0); STAGE_W(1);
    asm volatile("s_waitcnt vmcnt(2)" ::: "memory");
    asm volatile("s_barrier" ::: "memory");

    SUBPHASE(0);  SUBPHASE(1);  SUBPHASE(2);  SUBPHASE(3);
    SUBPHASE(4);  SUBPHASE(5);  SUBPHASE(6);  SUBPHASE(7);
    SUBPHASE(8);  SUBPHASE(9);  SUBPHASE(10); SUBPHASE(11);
    SUBPHASE(12); SUBPHASE(13); SUBPHASE(14); SUBPHASE(15);
    SUBPHASE(16); SUBPHASE(17); SUBPHASE(18); SUBPHASE(19);
    SUBPHASE(20); SUBPHASE(21); SUBPHASE(22); SUBPHASE(23);
    SUBPHASE(24); SUBPHASE(25); SUBPHASE(26); SUBPHASE(27);
    SUBPHASE(28); SUBPHASE(29); SUBPHASE(30); SUBPHASE(31);
    SUBPHASE(32); SUBPHASE(33); SUBPHASE(34); SUBPHASE(35);

#undef SUBPHASE
#undef STAGE_ROWS2
#undef STAGE_W

    // epilogue: D col = l15 (pixel), row = lk*4 + j (ko)
    const int sp0 = rb * 56 + wc * 112;
#pragma unroll
    for (int m = 0; m < 4; ++m) {
        int kb = wr * 64 + m * 16 + lk * 4;
        f32x4 bs = *(const f32x4*)(bias + kb);
#pragma unroll
        for (int nf = 0; nf < 7; ++nf) {
            float* ob = out + ((size_t)(n * K_OUT + kb) * IMG) + sp0 + nf * 16 + l15;
#pragma unroll
            for (int j = 0; j < 4; ++j)
                ob[(size_t)j * IMG] = acc[m][nf][j] + bs[j];
        }
    }
}

// ---- fallback (only if ws too small): naive fp32 direct conv ----
__global__ void conv_naive(const float* __restrict__ inp,
                           const float* __restrict__ ker,
                           const float* __restrict__ bias,
                           float* __restrict__ out, int total) {
    int o = blockIdx.x * blockDim.x + threadIdx.x;
    if (o >= total) return;
    int x = o % HW, y = (o / HW) % HW, ko = (o / IMG) % K_OUT, n = o / (IMG * K_OUT);
    float acc = bias[ko];
    for (int c = 0; c < C_IN; ++c)
        for (int r = 0; r < 3; ++r) {
            int iy = y + r - 1; if ((unsigned)iy >= HW) continue;
            for (int s = 0; s < 3; ++s) {
                int ix = x + s - 1; if ((unsigned)ix >= HW) continue;
                acc += inp[((n * C_IN + c) * HW + iy) * HW + ix]
                     * ker[((ko * C_IN + c) * 3 + r) * 3 + s];
            }
        }
    out[o] = acc;
}

extern "C" void kernel_launch(void* const* d_in, const int* in_sizes, int n_in,
                              void* d_out, int out_size, void* d_ws, size_t ws_size,
                              hipStream_t stream) {
    const float* inp  = (const float*)d_in[0];
    const float* ker  = (const float*)d_in[1];
    const float* bias = (const float*)d_in[2];
    float* out = (float*)d_out;

    const size_t need = (IN_WS_USHORT + WT_WS_USHORT) * 2;
    if (ws_size < need) {
        int total = NBATCH * K_OUT * IMG;
        conv_naive<<<(total + 255) / 256, 256, 0, stream>>>(inp, ker, bias, out, total);
        return;
    }

    unsigned short* inb = (unsigned short*)d_ws;
    unsigned short* wtb = inb + IN_WS_USHORT;

    prep_input<<<NBATCH * PW, 256, 0, stream>>>(inp, inb);
    prep_weights<<<144, 256, 0, stream>>>(ker, wtb);

    conv_mfma<<<448, 512, 0, stream>>>(inb, wtb, bias, out);
}